// Round 1
// 299.355 us; speedup vs baseline: 1.1895x; 1.1895x over previous
//
#include <hip/hip_runtime.h>
#include <hip/hip_fp16.h>
#include <cstdint>

typedef _Float16 f16x8 __attribute__((ext_vector_type(8)));
typedef _Float16 f16x4 __attribute__((ext_vector_type(4)));
typedef float    f32x4 __attribute__((ext_vector_type(4)));
typedef float    f32x16 __attribute__((ext_vector_type(16)));

#define MFMA16(a, b, c) __builtin_amdgcn_mfma_f32_16x16x32_f16((a), (b), (c), 0, 0, 0)
#define MFMA32(a, b, c) __builtin_amdgcn_mfma_f32_32x32x16_f16((a), (b), (c), 0, 0, 0)

// B=4, LQ=4096, LKV=256, D=1024, H=16, KVH=4, HD=64

__device__ __forceinline__ void async_cp16(const _Float16* g, _Float16* l) {
    __builtin_amdgcn_global_load_lds(
        (const __attribute__((address_space(1))) void*)g,
        (__attribute__((address_space(3))) void*)l, 16, 0, 0);
}

// ---------------------------------------------------------------------------
// fp32 -> fp16 convert for patches + latents in one launch
// ---------------------------------------------------------------------------
__global__ __launch_bounds__(256) void cvt_all(const float4* __restrict__ patches,
                                               const float4* __restrict__ latents,
                                               f16x4* __restrict__ p16,
                                               f16x4* __restrict__ l16) {
    const long i = (long)blockIdx.x * 256 + threadIdx.x;
    const float4 v = (i < 4194304) ? patches[i] : latents[i - 4194304];
    f16x4 o;
    o[0] = (_Float16)v.x; o[1] = (_Float16)v.y;
    o[2] = (_Float16)v.z; o[3] = (_Float16)v.w;
    if (i < 4194304) p16[i] = o; else l16[i - 4194304] = o;
}

// ---------------------------------------------------------------------------
// All 4 weight transposes (fp32 [K][N] -> fp16 [N][K]) in one launch.
// ---------------------------------------------------------------------------
__global__ __launch_bounds__(256) void transpose_all(
    const float* __restrict__ Wq, const float* __restrict__ Wk,
    const float* __restrict__ Wv, const float* __restrict__ Wo,
    _Float16* __restrict__ WqT, _Float16* __restrict__ WkvT,
    _Float16* __restrict__ WoT) {
    const int z = blockIdx.z;
    const float* W;
    _Float16* WT;
    int Nd;
    if (z == 0)      { W = Wq; WT = WqT;                       Nd = 1024; }
    else if (z == 1) { W = Wk; WT = WkvT;                      Nd = 256;  }
    else if (z == 2) { W = Wv; WT = WkvT + (size_t)256 * 1024; Nd = 256;  }
    else             { W = Wo; WT = WoT;                       Nd = 1024; }
    const int n0 = blockIdx.x * 64, k0 = blockIdx.y * 64;
    if (n0 >= Nd) return;

    __shared__ float T[64][65];
    const int tid = threadIdx.x;
    const int nl = tid & 63, kg = tid >> 6;
#pragma unroll
    for (int i = 0; i < 16; ++i) {
        const int kl = kg * 16 + i;
        T[kl][nl] = W[(size_t)(k0 + kl) * Nd + n0 + nl];
    }
    __syncthreads();
    const int kl = tid & 63;
#pragma unroll
    for (int i = 0; i < 16; ++i) {
        const int nl2 = kg * 16 + i;
        WT[(size_t)(n0 + nl2) * 1024 + k0 + kl] = (_Float16)T[kl][nl2];
    }
}

__global__ void catbias(const float* __restrict__ a, const float* __restrict__ b,
                        float* __restrict__ o) {
    const int i = threadIdx.x;  // 512 threads
    o[i] = (i < 256) ? a[i] : b[i - 256];
}

// ---------------------------------------------------------------------------
// GEMM: C(MxN) = A(MxK) @ BT(NxK)^T + bias.  A,BT fp16 [row][k].
// 32x32x16 MFMA. Block 256m x 128n, 4 waves, wave 128x64. BK=64, swizzled
// global_load_lds staging.
// XCD-aware block swizzle: default dispatch puts XCD = lin%8 = n-tile index,
// so every XCD streams the WHOLE A matrix (8x A refetch).  Remap so each XCD
// owns a contiguous stripe of m-tiles (n fastest within): A fetched once
// per XCD-stripe, B (2 MB) L2-resident per XCD.
//   EPI 0: Q-proj  (bias+RoPE+*0.125 -> fp16 q_h[b][h][lq][hd]),  N=1024
//   EPI 1: KV-proj (n<256: K bias+RoPE -> k_h[b][kvh][lkv][hd];
//                   n>=256: V bias -> v_pi[b][kvh][hd][s(lkv)]),  N=512
//   EPI 2: O-proj  (bias -> fp32 out row-major),                  N=1024
// ---------------------------------------------------------------------------
template <int EPI>
__global__ __launch_bounds__(256, 2) void gemm32(const _Float16* __restrict__ A,
                                                 const _Float16* __restrict__ BT,
                                                 const float* __restrict__ bias,
                                                 void* __restrict__ Cp,
                                                 const int* __restrict__ nfp) {
    constexpr int K = 1024;
    __shared__ _Float16 As[256 * 64];
    __shared__ _Float16 Bs[128 * 64];

    const int tid = threadIdx.x;
    const int lane = tid & 63, l31 = lane & 31, hh = lane >> 5;
    const int w = tid >> 6, wm = w >> 1, wn = w & 1;

    // bijective XCD swizzle (nwg % 8 == 0 for all EPIs)
    constexpr int GXS = (EPI == 1) ? 2 : 3;   // log2(gridDim.x)
    constexpr int NWG = (EPI == 1) ? 16 : 512;
    int lin = (blockIdx.y << GXS) + blockIdx.x;
    lin = (lin & 7) * (NWG >> 3) + (lin >> 3);
    const int n0 = (lin & ((1 << GXS) - 1)) * 128;
    const int m0 = (lin >> GXS) * 256;

    f32x16 acc[4][2];
#pragma unroll
    for (int mt = 0; mt < 4; ++mt)
#pragma unroll
        for (int nt = 0; nt < 2; ++nt)
#pragma unroll
            for (int v = 0; v < 16; ++v) acc[mt][nt][v] = 0.f;

    for (int k0 = 0; k0 < K; k0 += 64) {
#pragma unroll
        for (int i = 0; i < 8; ++i) {
            const int id = i * 256 + tid;
            const int r = id >> 3;
            const int c = (id & 7) ^ (r & 7);
            async_cp16(A + (size_t)(m0 + r) * K + k0 + c * 8,
                       As + i * 2048 + w * 512);
        }
#pragma unroll
        for (int i = 0; i < 4; ++i) {
            const int id = i * 256 + tid;
            const int r = id >> 3;
            const int c = (id & 7) ^ (r & 7);
            async_cp16(BT + (size_t)(n0 + r) * K + k0 + c * 8,
                       Bs + i * 2048 + w * 512);
        }
        __syncthreads();

#pragma unroll
        for (int kk = 0; kk < 4; ++kk) {
            f16x8 af[4], bf[2];
#pragma unroll
            for (int mt = 0; mt < 4; ++mt) {
                const int row = wm * 128 + mt * 32 + l31;
                const int pc = (kk * 2 + hh) ^ (row & 7);
                af[mt] = *(const f16x8*)&As[row * 64 + pc * 8];
            }
#pragma unroll
            for (int nt = 0; nt < 2; ++nt) {
                const int row = wn * 64 + nt * 32 + l31;
                const int pc = (kk * 2 + hh) ^ (row & 7);
                bf[nt] = *(const f16x8*)&Bs[row * 64 + pc * 8];
            }
#pragma unroll
            for (int mt = 0; mt < 4; ++mt)
#pragma unroll
                for (int nt = 0; nt < 2; ++nt)
                    acc[mt][nt] = MFMA32(af[mt], bf[nt], acc[mt][nt]);
        }
        __syncthreads();
    }

    const int nf = nfp[0];
    const int nbase = n0 + wn * 64;

    float bb[2];
#pragma unroll
    for (int nt = 0; nt < 2; ++nt) bb[nt] = bias[nbase + nt * 32 + l31];
#pragma unroll
    for (int mt = 0; mt < 4; ++mt)
#pragma unroll
        for (int nt = 0; nt < 2; ++nt)
#pragma unroll
            for (int v = 0; v < 16; ++v) acc[mt][nt][v] += bb[nt];

    if constexpr (EPI == 0) {  // Q: bias+RoPE+0.125 -> q_h[b][h][lq][hd]
        const float l2b = 13.287712379549449f;
        const float inv = exp2f(-((float)l31 * (1.0f / 32.0f)) * l2b);
        const int dv = 4096 / (nf > 1 ? nf : 1);
        _Float16* O = (_Float16*)Cp;
        const int head = nbase >> 6;
#pragma unroll
        for (int mt = 0; mt < 4; ++mt) {
#pragma unroll
            for (int v = 0; v < 16; ++v) {
                const int m = m0 + wm * 128 + mt * 32 + (v & 3) + 8 * (v >> 2) + 4 * hh;
                const int b = m >> 12, lq = m & 4095;
                if (nf > 1) {
                    const int pos = lq / dv;
                    float s, c;
                    __sincosf((float)pos * inv, &s, &c);
                    const float x1 = acc[mt][0][v], x2 = acc[mt][1][v];
                    acc[mt][0][v] = x1 * c - x2 * s;
                    acc[mt][1][v] = x2 * c + x1 * s;
                }
#pragma unroll
                for (int nt = 0; nt < 2; ++nt) {
                    const int hd = nt * 32 + l31;
                    O[(((size_t)(b * 16 + head)) * 4096 + lq) * 64 + hd] =
                        (_Float16)(acc[mt][nt][v] * 0.125f);
                }
            }
        }
    } else if constexpr (EPI == 1) {  // K/V fused (N=512)
        _Float16* kout = (_Float16*)Cp;
        _Float16* vout = kout + (size_t)4 * 4 * 256 * 64;
        if (nbase < 256) {
            const float l2b = 13.287712379549449f;
            const float inv = exp2f(-((float)l31 * (1.0f / 32.0f)) * l2b);
            const int dv = 256 / (nf > 1 ? nf : 1);
            const int kvh = nbase >> 6;
#pragma unroll
            for (int mt = 0; mt < 4; ++mt) {
#pragma unroll
                for (int v = 0; v < 16; ++v) {
                    const int m = m0 + wm * 128 + mt * 32 + (v & 3) + 8 * (v >> 2) + 4 * hh;
                    const int b = m >> 8, lkv = m & 255;
                    if (nf > 1) {
                        const int pos = lkv / dv;
                        float s, c;
                        __sincosf((float)pos * inv, &s, &c);
                        const float x1 = acc[mt][0][v], x2 = acc[mt][1][v];
                        acc[mt][0][v] = x1 * c - x2 * s;
                        acc[mt][1][v] = x2 * c + x1 * s;
                    }
#pragma unroll
                    for (int nt = 0; nt < 2; ++nt) {
                        const int hd = nt * 32 + l31;
                        kout[(((size_t)(b * 4 + kvh)) * 256 + lkv) * 64 + hd] =
                            (_Float16)acc[mt][nt][v];
                    }
                }
            }
        } else {
            const int kvh = (nbase - 256) >> 6;
#pragma unroll
            for (int mt = 0; mt < 4; ++mt) {
#pragma unroll
                for (int v = 0; v < 16; ++v) {
                    const int m = m0 + wm * 128 + mt * 32 + (v & 3) + 8 * (v >> 2) + 4 * hh;
                    const int b = m >> 8, lkv = m & 255;
                    // pi-permuted kv slot: swap the 16s bit below the 4s bits
                    const int s = (lkv & 0xE0) | ((lkv & 12) << 1) |
                                  ((lkv & 16) >> 2) | (lkv & 3);
#pragma unroll
                    for (int nt = 0; nt < 2; ++nt) {
                        const int hd = nt * 32 + l31;
                        vout[(((size_t)(b * 4 + kvh)) * 64 + hd) * 256 + s] =
                            (_Float16)acc[mt][nt][v];
                    }
                }
            }
        }
    } else {  // O-proj fp32
        float* O = (float*)Cp;
#pragma unroll
        for (int mt = 0; mt < 4; ++mt) {
#pragma unroll
            for (int v = 0; v < 16; ++v) {
                const int m = m0 + wm * 128 + mt * 32 + (v & 3) + 8 * (v >> 2) + 4 * hh;
#pragma unroll
                for (int nt = 0; nt < 2; ++nt)
                    O[(size_t)m * 1024 + nbase + nt * 32 + l31] = acc[mt][nt][v];
            }
        }
    }
}

// ---------------------------------------------------------------------------
// Attention v6.  Block = 8 waves = 512 q-rows of one (b,h); wave = 4 chunks
// of 16 q-rows.  K staged in LDS (32 KB, swizzled) as before; NEW: V_pi also
// staged in LDS (32 KB, 16B-chunk XOR swizzle s ^= (hd&7)<<2 -> the PV
// ds_read_b128 distributes 8 lanes per 4-bank group = b128 floor, conflict-
// free, ~130cy latency instead of ~300cy scattered L1-thrashed global loads).
// Q for chunk+1 is prefetched during chunk's compute; per-wave chunk order
// rotated by (w&3) to de-convoy the co-resident waves.
// LDS 64 KB/block -> 2 blocks/CU x 8 waves = 16 waves/CU (reg-capped at 4
// waves/SIMD anyway: st[16] = 64 f32 acc).  launch_bounds(512,4) caps
// VGPR+AGPR at 128 -> no spill, same occupancy as v5.
// Grid (bh, q/512): all 8 q-blocks of one bh land on XCD bh%8 -> K/V/Q slab
// per-XCD L2-hot.
// ---------------------------------------------------------------------------
__global__ __launch_bounds__(512, 4) void attn5(const _Float16* __restrict__ qh,
                                                const _Float16* __restrict__ kh,
                                                const _Float16* __restrict__ vp,
                                                _Float16* __restrict__ attn) {
    __shared__ _Float16 Ks[256 * 64];  // swizzled: chunk c of row r at c^(r&7)
    __shared__ _Float16 Vs[64 * 256];  // swizzled: chunk s of row hd at s^((hd&7)<<2)

    const int tid = threadIdx.x;
    const int w = tid >> 6, lane = tid & 63, quad = lane >> 4, l15 = lane & 15;
    const int bh = blockIdx.x, b = bh >> 4, h = bh & 15, kvh = h >> 2;
    const int q0 = blockIdx.y * 512;

    const _Float16* kb = kh + (size_t)(b * 4 + kvh) * 256 * 64;
    const _Float16* vb = vp + (size_t)(b * 4 + kvh) * 64 * 256;
    const _Float16* qb = qh + ((size_t)bh * 4096 + q0) * 64;

    // ---- stage K into LDS (2048 x 16B chunks, 4/thread), source-swizzled
#pragma unroll
    for (int i = 0; i < 4; ++i) {
        const int id = i * 512 + tid;
        const int r = id >> 3;
        const int c = (id & 7) ^ (r & 7);
        async_cp16(kb + (size_t)r * 64 + c * 8, Ks + i * 4096 + w * 512);
    }
    // ---- stage V_pi into LDS (2048 x 16B chunks), source-swizzled:
    // dest chunk (hd, s5) holds global chunk s5 ^ ((hd&7)<<2) of row hd
#pragma unroll
    for (int i = 0; i < 4; ++i) {
        const int id = i * 512 + tid;
        const int hd = id >> 5;
        const int s5 = id & 31;
        const int c = s5 ^ ((hd & 7) << 2);
        async_cp16(vb + (size_t)hd * 256 + c * 8, Vs + i * 4096 + w * 512);
    }
    __syncthreads();

    const int sw = l15 & 7;        // K read-side swizzle key (row&7 == l15&7)
    const int p0 = quad ^ sw;      // slot of k-chunk quad (hd 0..31)
    const int vsw = sw << 2;       // V read-side swizzle key (hd&7 == l15&7)
    const int crot = w & 3;        // per-wave chunk rotation (de-convoy)

    // prefetch Q for first chunk
    const _Float16* qpre = qb + (size_t)(w * 64 + crot * 16 + l15) * 64 + quad * 8;
    f16x8 bq0 = *(const f16x8*)qpre;
    f16x8 bq1 = *(const f16x8*)(qpre + 32);

#pragma unroll 1
    for (int cc = 0; cc < 4; ++cc) {
        const int chunk = (cc + crot) & 3;
        const int qrow = w * 64 + chunk * 16;

        // issue next chunk's Q loads now; consumed next iteration
        // (cc==3 wraps to an already-done chunk: 1 redundant 32B load, harmless)
        const int nchunk = (cc + 1 + crot) & 3;
        const _Float16* np = qb + (size_t)(w * 64 + nchunk * 16 + l15) * 64 + quad * 8;
        const f16x8 nq0 = *(const f16x8*)np;
        const f16x8 nq1 = *(const f16x8*)(np + 32);

        // S^T = K @ Q^T : lane holds S[q=l15][kv = t*16 + quad*4 + rr]
        f32x4 st[16];
#pragma unroll
        for (int t = 0; t < 16; ++t)
#pragma unroll
            for (int rr = 0; rr < 4; ++rr) st[t][rr] = 0.f;

#pragma unroll
        for (int t = 0; t < 16; ++t) {
            const int row = t * 16 + l15;
            const f16x8 ka0 = *(const f16x8*)&Ks[row * 64 + p0 * 8];
            const f16x8 ka1 = *(const f16x8*)&Ks[row * 64 + (p0 ^ 4) * 8];
            st[t] = MFMA16(ka0, bq0, st[t]);
            st[t] = MFMA16(ka1, bq1, st[t]);
        }

        // softmax over 256 kv (row q = l15 -> 2 shuffles)
        float rm = -1e30f;
#pragma unroll
        for (int t = 0; t < 16; ++t)
#pragma unroll
            for (int rr = 0; rr < 4; ++rr) rm = fmaxf(rm, st[t][rr]);
        rm = fmaxf(rm, __shfl_xor(rm, 16, 64));
        rm = fmaxf(rm, __shfl_xor(rm, 32, 64));

        float rs = 0.f;
#pragma unroll
        for (int t = 0; t < 16; ++t) {
#pragma unroll
            for (int rr = 0; rr < 4; ++rr) {
                st[t][rr] = __expf(st[t][rr] - rm);
                rs += st[t][rr];
            }
        }
        rs += __shfl_xor(rs, 16, 64);
        rs += __shfl_xor(rs, 32, 64);
        const float ir = 1.0f / rs;  // per-lane correct for q = l15

        // opaque 0 offset: keep the 32 V ds_reads inside this iteration
        // (LICM hoisting them across chunks would blow the 128-reg budget)
        int vo = 0;
        asm volatile("" : "+v"(vo));

        // O^T = V_pi @ P^T : 4 hd-tiles, k = 256 in 8 chunks of 32
        f32x4 o[4];
#pragma unroll
        for (int nt = 0; nt < 4; ++nt)
#pragma unroll
            for (int rr = 0; rr < 4; ++rr) o[nt][rr] = 0.f;

#pragma unroll
        for (int c = 0; c < 8; ++c) {
            // P^T B-frag: slot (quad, j) <-> kv = 32c + 16*(j>>2) + 4*quad + (j&3)
            f16x8 pb;
#pragma unroll
            for (int j = 0; j < 8; ++j)
                pb[j] = (_Float16)st[2 * c + (j >> 2)][j & 3];
#pragma unroll
            for (int nt = 0; nt < 4; ++nt) {
                const f16x8 va = *(const f16x8*)&Vs[(nt * 16 + l15) * 256 +
                                                   (((c * 4 + quad) ^ vsw) * 8) + vo];
                o[nt] = MFMA16(va, pb, o[nt]);
            }
        }

        // store: O^T C-frag: q = l15, hd = nt*16 + quad*4 + rr -> f16x4 packs
        const size_t rowbase = ((size_t)b * 4096 + q0 + qrow + l15) * 1024 + h * 64;
#pragma unroll
        for (int nt = 0; nt < 4; ++nt) {
            f16x4 ov;
#pragma unroll
            for (int rr = 0; rr < 4; ++rr) ov[rr] = (_Float16)(o[nt][rr] * ir);
            *(f16x4*)&attn[rowbase + nt * 16 + quad * 4] = ov;
        }

        bq0 = nq0; bq1 = nq1;
    }
}

// ---------------------------------------------------------------------------
extern "C" void kernel_launch(void* const* d_in, const int* in_sizes, int n_in,
                              void* d_out, int out_size, void* d_ws, size_t ws_size,
                              hipStream_t stream) {
    const float* patches = (const float*)d_in[0];
    const float* latents = (const float*)d_in[1];
    const float* Wq = (const float*)d_in[2];
    const float* bq = (const float*)d_in[3];
    const float* Wk = (const float*)d_in[4];
    const float* bk = (const float*)d_in[5];
    const float* Wv = (const float*)d_in[6];
    const float* bv = (const float*)d_in[7];
    const float* Wo = (const float*)d_in[8];
    const float* bo = (const float*)d_in[9];
    const int*   nf = (const int*)d_in[10];
    float* out = (float*)d_out;
    (void)in_sizes; (void)n_in; (void)out_size; (void)ws_size;

    char* p = (char*)d_ws;
    _Float16* WqT  = (_Float16*)p; p += (size_t)1024 * 1024 * 2;
    _Float16* WkvT = (_Float16*)p; p += (size_t)512 * 1024 * 2;
    _Float16* WoT  = (_Float16*)p; p += (size_t)1024 * 1024 * 2;
    float*    bkv  = (float*)p;    p += 4096;
    _Float16* p16  = (_Float16*)p; p += (size_t)4 * 4096 * 1024 * 2;
    _Float16* l16  = (_Float16*)p; p += (size_t)4 * 256 * 1024 * 2;
    _Float16* q_h  = (_Float16*)p; p += (size_t)4 * 16 * 4096 * 64 * 2;
    _Float16* k_h  = (_Float16*)p; p += (size_t)4 * 4 * 256 * 64 * 2;
    _Float16* v_pi = (_Float16*)p; p += (size_t)4 * 4 * 256 * 64 * 2;  // after k_h
    _Float16* attn_h = (_Float16*)p; p += (size_t)16384 * 1024 * 2;

    cvt_all<<<17408, 256, 0, stream>>>((const float4*)patches, (const float4*)latents,
                                       (f16x4*)p16, (f16x4*)l16);
    transpose_all<<<dim3(16, 16, 4), 256, 0, stream>>>(Wq, Wk, Wv, Wo, WqT, WkvT, WoT);
    catbias<<<1, 512, 0, stream>>>(bk, bv, bkv);

    gemm32<1><<<dim3(4, 4), 256, 0, stream>>>(l16, WkvT, bkv, k_h, nf);
    gemm32<0><<<dim3(8, 64), 256, 0, stream>>>(p16, WqT, bq, q_h, nf);

    attn5<<<dim3(64, 8), 512, 0, stream>>>(q_h, k_h, v_pi, attn_h);

    gemm32<2><<<dim3(8, 64), 256, 0, stream>>>(attn_h, WoT, bo, out, nf);
}

// Round 2
// 284.573 us; speedup vs baseline: 1.2513x; 1.0519x over previous
//
#include <hip/hip_runtime.h>
#include <hip/hip_fp16.h>
#include <cstdint>

typedef _Float16 f16x8 __attribute__((ext_vector_type(8)));
typedef _Float16 f16x4 __attribute__((ext_vector_type(4)));
typedef float    f32x4 __attribute__((ext_vector_type(4)));
typedef float    f32x16 __attribute__((ext_vector_type(16)));

#define MFMA16(a, b, c) __builtin_amdgcn_mfma_f32_16x16x32_f16((a), (b), (c), 0, 0, 0)
#define MFMA32(a, b, c) __builtin_amdgcn_mfma_f32_32x32x16_f16((a), (b), (c), 0, 0, 0)

// B=4, LQ=4096, LKV=256, D=1024, H=16, KVH=4, HD=64

__device__ __forceinline__ void async_cp16(const _Float16* g, _Float16* l) {
    __builtin_amdgcn_global_load_lds(
        (const __attribute__((address_space(1))) void*)g,
        (__attribute__((address_space(3))) void*)l, 16, 0, 0);
}

// ---------------------------------------------------------------------------
// fp32 -> fp16 convert for patches + latents in one launch
// ---------------------------------------------------------------------------
__global__ __launch_bounds__(256) void cvt_all(const float4* __restrict__ patches,
                                               const float4* __restrict__ latents,
                                               f16x4* __restrict__ p16,
                                               f16x4* __restrict__ l16) {
    const long i = (long)blockIdx.x * 256 + threadIdx.x;
    const float4 v = (i < 4194304) ? patches[i] : latents[i - 4194304];
    f16x4 o;
    o[0] = (_Float16)v.x; o[1] = (_Float16)v.y;
    o[2] = (_Float16)v.z; o[3] = (_Float16)v.w;
    if (i < 4194304) p16[i] = o; else l16[i - 4194304] = o;
}

// ---------------------------------------------------------------------------
// All 4 weight transposes (fp32 [K][N] -> fp16 [N][K]) in one launch.
// ---------------------------------------------------------------------------
__global__ __launch_bounds__(256) void transpose_all(
    const float* __restrict__ Wq, const float* __restrict__ Wk,
    const float* __restrict__ Wv, const float* __restrict__ Wo,
    _Float16* __restrict__ WqT, _Float16* __restrict__ WkvT,
    _Float16* __restrict__ WoT) {
    const int z = blockIdx.z;
    const float* W;
    _Float16* WT;
    int Nd;
    if (z == 0)      { W = Wq; WT = WqT;                       Nd = 1024; }
    else if (z == 1) { W = Wk; WT = WkvT;                      Nd = 256;  }
    else if (z == 2) { W = Wv; WT = WkvT + (size_t)256 * 1024; Nd = 256;  }
    else             { W = Wo; WT = WoT;                       Nd = 1024; }
    const int n0 = blockIdx.x * 64, k0 = blockIdx.y * 64;
    if (n0 >= Nd) return;

    __shared__ float T[64][65];
    const int tid = threadIdx.x;
    const int nl = tid & 63, kg = tid >> 6;
#pragma unroll
    for (int i = 0; i < 16; ++i) {
        const int kl = kg * 16 + i;
        T[kl][nl] = W[(size_t)(k0 + kl) * Nd + n0 + nl];
    }
    __syncthreads();
    const int kl = tid & 63;
#pragma unroll
    for (int i = 0; i < 16; ++i) {
        const int nl2 = kg * 16 + i;
        WT[(size_t)(n0 + nl2) * 1024 + k0 + kl] = (_Float16)T[kl][nl2];
    }
}

__global__ void catbias(const float* __restrict__ a, const float* __restrict__ b,
                        float* __restrict__ o) {
    const int i = threadIdx.x;  // 512 threads
    o[i] = (i < 256) ? a[i] : b[i - 256];
}

// ---------------------------------------------------------------------------
// Small-M GEMM (KV-proj only): old 2-barrier structure, 256x128 tile.
// ---------------------------------------------------------------------------
template <int EPI>
__global__ __launch_bounds__(256, 2) void gemm32(const _Float16* __restrict__ A,
                                                 const _Float16* __restrict__ BT,
                                                 const float* __restrict__ bias,
                                                 void* __restrict__ Cp,
                                                 const int* __restrict__ nfp) {
    constexpr int K = 1024;
    __shared__ _Float16 As[256 * 64];
    __shared__ _Float16 Bs[128 * 64];

    const int tid = threadIdx.x;
    const int lane = tid & 63, l31 = lane & 31, hh = lane >> 5;
    const int w = tid >> 6, wm = w >> 1, wn = w & 1;

    const int n0 = blockIdx.x * 128;
    const int m0 = blockIdx.y * 256;

    f32x16 acc[4][2];
#pragma unroll
    for (int mt = 0; mt < 4; ++mt)
#pragma unroll
        for (int nt = 0; nt < 2; ++nt)
#pragma unroll
            for (int v = 0; v < 16; ++v) acc[mt][nt][v] = 0.f;

    for (int k0 = 0; k0 < K; k0 += 64) {
#pragma unroll
        for (int i = 0; i < 8; ++i) {
            const int id = i * 256 + tid;
            const int r = id >> 3;
            const int c = (id & 7) ^ (r & 7);
            async_cp16(A + (size_t)(m0 + r) * K + k0 + c * 8,
                       As + i * 2048 + w * 512);
        }
#pragma unroll
        for (int i = 0; i < 4; ++i) {
            const int id = i * 256 + tid;
            const int r = id >> 3;
            const int c = (id & 7) ^ (r & 7);
            async_cp16(BT + (size_t)(n0 + r) * K + k0 + c * 8,
                       Bs + i * 2048 + w * 512);
        }
        __syncthreads();

#pragma unroll
        for (int kk = 0; kk < 4; ++kk) {
            f16x8 af[4], bf[2];
#pragma unroll
            for (int mt = 0; mt < 4; ++mt) {
                const int row = wm * 128 + mt * 32 + l31;
                const int pc = (kk * 2 + hh) ^ (row & 7);
                af[mt] = *(const f16x8*)&As[row * 64 + pc * 8];
            }
#pragma unroll
            for (int nt = 0; nt < 2; ++nt) {
                const int row = wn * 64 + nt * 32 + l31;
                const int pc = (kk * 2 + hh) ^ (row & 7);
                bf[nt] = *(const f16x8*)&Bs[row * 64 + pc * 8];
            }
#pragma unroll
            for (int mt = 0; mt < 4; ++mt)
#pragma unroll
                for (int nt = 0; nt < 2; ++nt)
                    acc[mt][nt] = MFMA32(af[mt], bf[nt], acc[mt][nt]);
        }
        __syncthreads();
    }

    const int nf = nfp[0];
    const int nbase = n0 + wn * 64;

    float bb[2];
#pragma unroll
    for (int nt = 0; nt < 2; ++nt) bb[nt] = bias[nbase + nt * 32 + l31];
#pragma unroll
    for (int mt = 0; mt < 4; ++mt)
#pragma unroll
        for (int nt = 0; nt < 2; ++nt)
#pragma unroll
            for (int v = 0; v < 16; ++v) acc[mt][nt][v] += bb[nt];

    {  // K/V fused (N=512)
        _Float16* kout = (_Float16*)Cp;
        _Float16* vout = kout + (size_t)4 * 4 * 256 * 64;
        if (nbase < 256) {
            const float l2b = 13.287712379549449f;
            const float inv = exp2f(-((float)l31 * (1.0f / 32.0f)) * l2b);
            const int dv = 256 / (nf > 1 ? nf : 1);
            const int kvh = nbase >> 6;
#pragma unroll
            for (int mt = 0; mt < 4; ++mt) {
#pragma unroll
                for (int v = 0; v < 16; ++v) {
                    const int m = m0 + wm * 128 + mt * 32 + (v & 3) + 8 * (v >> 2) + 4 * hh;
                    const int b = m >> 8, lkv = m & 255;
                    if (nf > 1) {
                        const int pos = lkv / dv;
                        float s, c;
                        __sincosf((float)pos * inv, &s, &c);
                        const float x1 = acc[mt][0][v], x2 = acc[mt][1][v];
                        acc[mt][0][v] = x1 * c - x2 * s;
                        acc[mt][1][v] = x2 * c + x1 * s;
                    }
#pragma unroll
                    for (int nt = 0; nt < 2; ++nt) {
                        const int hd = nt * 32 + l31;
                        kout[(((size_t)(b * 4 + kvh)) * 256 + lkv) * 64 + hd] =
                            (_Float16)acc[mt][nt][v];
                    }
                }
            }
        } else {
            const int kvh = (nbase - 256) >> 6;
#pragma unroll
            for (int mt = 0; mt < 4; ++mt) {
#pragma unroll
                for (int v = 0; v < 16; ++v) {
                    const int m = m0 + wm * 128 + mt * 32 + (v & 3) + 8 * (v >> 2) + 4 * hh;
                    const int b = m >> 8, lkv = m & 255;
                    // pi-permuted kv slot: swap the 16s bit below the 4s bits
                    const int s = (lkv & 0xE0) | ((lkv & 12) << 1) |
                                  ((lkv & 16) >> 2) | (lkv & 3);
#pragma unroll
                    for (int nt = 0; nt < 2; ++nt) {
                        const int hd = nt * 32 + l31;
                        vout[(((size_t)(b * 4 + kvh)) * 64 + hd) * 256 + s] =
                            (_Float16)acc[mt][nt][v];
                    }
                }
            }
        }
    }
}

// ---------------------------------------------------------------------------
// 8-phase 256x256 GEMM (T2+T3+T4+T5), for the two big GEMMs (M=16384,N=1024,
// K=1024).  512 threads = 8 waves (2m x 4n), wave output 128x64, MFMA
// 16x16x32.  LDS 128 KiB: [buf][A/B][half][128x64], 16B-chunk XOR swizzle
// c^(row&7) (attn5's pattern, 0 conflicts).  Per phase: {ds_read subtile;
// issue 1 half-tile global_load_lds; barrier; lgkmcnt(0); setprio(1);
// 16 MFMA; setprio(0); barrier}.  vmcnt(4) only at phases 4/8 (2 half-tiles
// stay in flight across barriers; never vmcnt(0) in the loop).
// Stage/read ledger (iteration = tiles t0=2i->buf0, t1=2i+1->buf1):
//   P0: rd A0[mf0-3]+B0[nf0-1] (12) | st hB1(t1)   | mfma t0 q(0,0)
//   P1: rd B0[nf2-3]            (4) | st hA1(t1)   | mfma t0 q(0,1)
//   P2: rd A0[mf4-7]            (8) | st hB0(t0+2) | mfma t0 q(1,0)
//   P3: --                          | st hB1(t0+2) | mfma t0 q(1,1) vmcnt(4)
//   P4: rd A1[mf0-3]+B1[nf0-1] (12) | st hA0(t0+2) | mfma t1 q(0,0)
//   P5: rd B1[nf2-3]            (4) | st hA1(t0+2) | mfma t1 q(0,1)
//   P6: rd A1[mf4-7]            (8) | st hB0(t1+2) | mfma t1 q(1,0)
//   P7: --                          | st hA0(t1+2) | mfma t1 q(1,1) vmcnt(4)
// Safety: every stage targets a region whose last ds_reads happened >=1 phase
// earlier (A halves die at P2/P6, B halves at P1/P5); every ds_read touches a
// half confirmed by each wave's own vmcnt(4) + a later block barrier.
// Grid 256 blocks = 1/CU, XCD-swizzled m-stripes (A panel 4MB + B 2MB / XCD).
//   EPI 0: Q-proj (bias+RoPE+*0.125 -> fp16 q_h),  EPI 2: O-proj (fp32).
// ---------------------------------------------------------------------------
template <int EPI>
__global__ __launch_bounds__(512, 2) void gemm8p(const _Float16* __restrict__ A,
                                                 const _Float16* __restrict__ BT,
                                                 const float* __restrict__ bias,
                                                 void* __restrict__ Cp,
                                                 const int* __restrict__ nfp) {
    constexpr int K = 1024;
    __shared__ alignas(16) _Float16 lds[2][2][2][128 * 64];  // [buf][A=0/B=1][half]

    const int tid = threadIdx.x;
    const int lane = tid & 63, quad = lane >> 4, l15 = lane & 15;
    const int w = tid >> 6, wm = w >> 2, wn = w & 3;

    // bijective XCD swizzle: 256 blocks, 8 XCDs -> 32-block m-stripes
    int lin = blockIdx.x;
    lin = (lin & 7) * 32 + (lin >> 3);
    const int m0 = (lin >> 2) * 256;
    const int n0 = (lin & 3) * 256;

    f32x4 acc[8][4];
#pragma unroll
    for (int mf = 0; mf < 8; ++mf)
#pragma unroll
        for (int nf = 0; nf < 4; ++nf)
#pragma unroll
            for (int rr = 0; rr < 4; ++rr) acc[mf][nf][rr] = 0.f;

    f16x8 ra[4][2], rb[4][2];

#define STAGE(BUF, MAT, HALF, KK0)                                              \
    {                                                                           \
        const _Float16* g_ = (MAT) ? BT : A;                                    \
        const int rb_ = ((MAT) ? n0 : m0) + (HALF) * 128;                       \
        _Float16* dst_ = &lds[BUF][MAT][HALF][0];                               \
        _Pragma("unroll") for (int i_ = 0; i_ < 2; ++i_) {                      \
            const int id_ = i_ * 512 + tid;                                     \
            const int r_ = id_ >> 3;                                            \
            const int c_ = (id_ & 7) ^ (r_ & 7);                                \
            async_cp16(g_ + (size_t)(rb_ + r_) * K + (KK0) + c_ * 8,            \
                       dst_ + i_ * 4096 + w * 512);                             \
        }                                                                       \
    }

#define LDA4(BUF, MH)                                                           \
    _Pragma("unroll") for (int i_ = 0; i_ < 4; ++i_)                            \
    _Pragma("unroll") for (int ks_ = 0; ks_ < 2; ++ks_) {                       \
        const int row_ = ((MH) * 4 + i_) * 16 + l15;                            \
        ra[i_][ks_] = *(const f16x8*)&lds[BUF][0][wm]                           \
            [row_ * 64 + (((ks_ * 4 + quad) ^ (l15 & 7)) * 8)];                 \
    }

#define LDB2(BUF, NFROM)                                                        \
    _Pragma("unroll") for (int j_ = 0; j_ < 2; ++j_)                            \
    _Pragma("unroll") for (int ks_ = 0; ks_ < 2; ++ks_) {                       \
        const int nf_ = (NFROM) + j_;                                           \
        const int row_ = (wn & 1) * 64 + nf_ * 16 + l15;                        \
        rb[nf_][ks_] = *(const f16x8*)&lds[BUF][1][wn >> 1]                     \
            [row_ * 64 + (((ks_ * 4 + quad) ^ (l15 & 7)) * 8)];                 \
    }

#define QUAD(QM, QN)                                                            \
    {                                                                           \
        __builtin_amdgcn_s_setprio(1);                                          \
        _Pragma("unroll") for (int i_ = 0; i_ < 4; ++i_)                        \
        _Pragma("unroll") for (int j_ = 0; j_ < 2; ++j_)                        \
        _Pragma("unroll") for (int ks_ = 0; ks_ < 2; ++ks_)                     \
            acc[(QM) * 4 + i_][(QN) * 2 + j_] =                                 \
                MFMA16(ra[i_][ks_], rb[(QN) * 2 + j_][ks_],                     \
                       acc[(QM) * 4 + i_][(QN) * 2 + j_]);                      \
        __builtin_amdgcn_s_setprio(0);                                          \
    }

#define FENCE() asm volatile("" ::: "memory")
#define BARR()  FENCE(); __builtin_amdgcn_s_barrier(); FENCE()
#define LGKM0() asm volatile("s_waitcnt lgkmcnt(0)" ::: "memory");              \
                __builtin_amdgcn_sched_barrier(0)
#define VMC4()  asm volatile("s_waitcnt vmcnt(4)" ::: "memory")

    // prologue: tile0 (all 4 halves) + tile1 (B0, A0)
    STAGE(0, 1, 0, 0);
    STAGE(0, 1, 1, 0);
    STAGE(0, 0, 0, 0);
    STAGE(0, 0, 1, 0);
    STAGE(1, 1, 0, 64);
    STAGE(1, 0, 0, 64);
    VMC4();
    BARR();

    int k0 = 0;
#pragma unroll 1
    for (int it = 0; it < 8; ++it) {
        const int k_t1 = k0 + 64;
        const int k_n0 = (k0 + 128 < K) ? k0 + 128 : K - 64;  // tile t0+2
        const int k_n1 = (k0 + 192 < K) ? k0 + 192 : K - 64;  // tile t1+2
        // P0
        LDA4(0, 0); LDB2(0, 0);
        STAGE(1, 1, 1, k_t1);
        BARR(); LGKM0(); QUAD(0, 0); BARR();
        // P1
        LDB2(0, 2);
        STAGE(1, 0, 1, k_t1);
        BARR(); LGKM0(); QUAD(0, 1); BARR();
        // P2
        LDA4(0, 1);
        STAGE(0, 1, 0, k_n0);
        BARR(); LGKM0(); QUAD(1, 0); BARR();
        // P3
        STAGE(0, 1, 1, k_n0);
        BARR(); LGKM0(); QUAD(1, 1); VMC4(); BARR();
        // P4
        LDA4(1, 0); LDB2(1, 0);
        STAGE(0, 0, 0, k_n0);
        BARR(); LGKM0(); QUAD(0, 0); BARR();
        // P5
        LDB2(1, 2);
        STAGE(0, 0, 1, k_n0);
        BARR(); LGKM0(); QUAD(0, 1); BARR();
        // P6
        LDA4(1, 1);
        STAGE(1, 1, 0, k_n1);
        BARR(); LGKM0(); QUAD(1, 0); BARR();
        // P7
        STAGE(1, 0, 0, k_n1);
        BARR(); LGKM0(); QUAD(1, 1); VMC4(); BARR();
        k0 += 128;
    }
    asm volatile("s_waitcnt vmcnt(0)" ::: "memory");

    // ---- epilogue: m = m0 + wm*128 + mf*16 + quad*4 + rr,
    //                n = n0 + wn*64 + nf*16 + l15
    const int nf_frames = nfp[0];
    float bb[4];
#pragma unroll
    for (int nf = 0; nf < 4; ++nf) bb[nf] = bias[n0 + wn * 64 + nf * 16 + l15];
#pragma unroll
    for (int mf = 0; mf < 8; ++mf)
#pragma unroll
        for (int nf = 0; nf < 4; ++nf)
#pragma unroll
            for (int rr = 0; rr < 4; ++rr) acc[mf][nf][rr] += bb[nf];

    if constexpr (EPI == 0) {  // Q-proj: RoPE + *0.125 -> q_h[b][h][lq][hd]
        const float l2b = 13.287712379549449f;
        const float inv0 = exp2f(-((float)l15 * (1.0f / 32.0f)) * l2b);
        const float inv1 = exp2f(-((float)(16 + l15) * (1.0f / 32.0f)) * l2b);
        const int dv = 4096 / (nf_frames > 1 ? nf_frames : 1);
        _Float16* O = (_Float16*)Cp;
        const int head = (n0 + wn * 64) >> 6;
#pragma unroll
        for (int mf = 0; mf < 8; ++mf) {
#pragma unroll
            for (int rr = 0; rr < 4; ++rr) {
                const int m = m0 + wm * 128 + mf * 16 + quad * 4 + rr;
                const int b = m >> 12, lq = m & 4095;
                if (nf_frames > 1) {
                    const int pos = lq / dv;
                    float s0, c0, s1, c1;
                    __sincosf((float)pos * inv0, &s0, &c0);
                    __sincosf((float)pos * inv1, &s1, &c1);
                    const float x0 = acc[mf][0][rr], x2 = acc[mf][2][rr];
                    const float x1 = acc[mf][1][rr], x3 = acc[mf][3][rr];
                    acc[mf][0][rr] = x0 * c0 - x2 * s0;
                    acc[mf][2][rr] = x2 * c0 + x0 * s0;
                    acc[mf][1][rr] = x1 * c1 - x3 * s1;
                    acc[mf][3][rr] = x3 * c1 + x1 * s1;
                }
                const size_t base = (((size_t)(b * 16 + head)) * 4096 + lq) * 64;
#pragma unroll
                for (int nf = 0; nf < 4; ++nf)
                    O[base + nf * 16 + l15] = (_Float16)(acc[mf][nf][rr] * 0.125f);
            }
        }
    } else {  // O-proj fp32 row-major
        float* O = (float*)Cp;
#pragma unroll
        for (int mf = 0; mf < 8; ++mf) {
#pragma unroll
            for (int rr = 0; rr < 4; ++rr) {
                const int m = m0 + wm * 128 + mf * 16 + quad * 4 + rr;
#pragma unroll
                for (int nf = 0; nf < 4; ++nf)
                    O[(size_t)m * 1024 + n0 + wn * 64 + nf * 16 + l15] =
                        acc[mf][nf][rr];
            }
        }
    }
#undef STAGE
#undef LDA4
#undef LDB2
#undef QUAD
#undef FENCE
#undef BARR
#undef LGKM0
#undef VMC4
}

// ---------------------------------------------------------------------------
// Attention v6.  Block = 8 waves = 512 q-rows of one (b,h); wave = 4 chunks
// of 16 q-rows.  K and V_pi staged in LDS (32 KB each, 16B-chunk XOR
// swizzles), Q prefetched one chunk ahead, per-wave chunk rotation.
// ---------------------------------------------------------------------------
__global__ __launch_bounds__(512, 4) void attn5(const _Float16* __restrict__ qh,
                                                const _Float16* __restrict__ kh,
                                                const _Float16* __restrict__ vp,
                                                _Float16* __restrict__ attn) {
    __shared__ _Float16 Ks[256 * 64];  // swizzled: chunk c of row r at c^(r&7)
    __shared__ _Float16 Vs[64 * 256];  // swizzled: chunk s of row hd at s^((hd&7)<<2)

    const int tid = threadIdx.x;
    const int w = tid >> 6, lane = tid & 63, quad = lane >> 4, l15 = lane & 15;
    const int bh = blockIdx.x, b = bh >> 4, h = bh & 15, kvh = h >> 2;
    const int q0 = blockIdx.y * 512;

    const _Float16* kb = kh + (size_t)(b * 4 + kvh) * 256 * 64;
    const _Float16* vb = vp + (size_t)(b * 4 + kvh) * 64 * 256;
    const _Float16* qb = qh + ((size_t)bh * 4096 + q0) * 64;

    // ---- stage K into LDS (2048 x 16B chunks, 4/thread), source-swizzled
#pragma unroll
    for (int i = 0; i < 4; ++i) {
        const int id = i * 512 + tid;
        const int r = id >> 3;
        const int c = (id & 7) ^ (r & 7);
        async_cp16(kb + (size_t)r * 64 + c * 8, Ks + i * 4096 + w * 512);
    }
    // ---- stage V_pi into LDS (2048 x 16B chunks), source-swizzled
#pragma unroll
    for (int i = 0; i < 4; ++i) {
        const int id = i * 512 + tid;
        const int hd = id >> 5;
        const int s5 = id & 31;
        const int c = s5 ^ ((hd & 7) << 2);
        async_cp16(vb + (size_t)hd * 256 + c * 8, Vs + i * 4096 + w * 512);
    }
    __syncthreads();

    const int sw = l15 & 7;        // K read-side swizzle key (row&7 == l15&7)
    const int p0 = quad ^ sw;      // slot of k-chunk quad (hd 0..31)
    const int vsw = sw << 2;       // V read-side swizzle key (hd&7 == l15&7)
    const int crot = w & 3;        // per-wave chunk rotation (de-convoy)

    // prefetch Q for first chunk
    const _Float16* qpre = qb + (size_t)(w * 64 + crot * 16 + l15) * 64 + quad * 8;
    f16x8 bq0 = *(const f16x8*)qpre;
    f16x8 bq1 = *(const f16x8*)(qpre + 32);

#pragma unroll 1
    for (int cc = 0; cc < 4; ++cc) {
        const int chunk = (cc + crot) & 3;
        const int qrow = w * 64 + chunk * 16;

        // issue next chunk's Q loads now; consumed next iteration
        const int nchunk = (cc + 1 + crot) & 3;
        const _Float16* np = qb + (size_t)(w * 64 + nchunk * 16 + l15) * 64 + quad * 8;
        const f16x8 nq0 = *(const f16x8*)np;
        const f16x8 nq1 = *(const f16x8*)(np + 32);

        // S^T = K @ Q^T : lane holds S[q=l15][kv = t*16 + quad*4 + rr]
        f32x4 st[16];
#pragma unroll
        for (int t = 0; t < 16; ++t)
#pragma unroll
            for (int rr = 0; rr < 4; ++rr) st[t][rr] = 0.f;

#pragma unroll
        for (int t = 0; t < 16; ++t) {
            const int row = t * 16 + l15;
            const f16x8 ka0 = *(const f16x8*)&Ks[row * 64 + p0 * 8];
            const f16x8 ka1 = *(const f16x8*)&Ks[row * 64 + (p0 ^ 4) * 8];
            st[t] = MFMA16(ka0, bq0, st[t]);
            st[t] = MFMA16(ka1, bq1, st[t]);
        }

        // softmax over 256 kv (row q = l15 -> 2 shuffles)
        float rm = -1e30f;
#pragma unroll
        for (int t = 0; t < 16; ++t)
#pragma unroll
            for (int rr = 0; rr < 4; ++rr) rm = fmaxf(rm, st[t][rr]);
        rm = fmaxf(rm, __shfl_xor(rm, 16, 64));
        rm = fmaxf(rm, __shfl_xor(rm, 32, 64));

        float rs = 0.f;
#pragma unroll
        for (int t = 0; t < 16; ++t) {
#pragma unroll
            for (int rr = 0; rr < 4; ++rr) {
                st[t][rr] = __expf(st[t][rr] - rm);
                rs += st[t][rr];
            }
        }
        rs += __shfl_xor(rs, 16, 64);
        rs += __shfl_xor(rs, 32, 64);
        const float ir = 1.0f / rs;  // per-lane correct for q = l15

        // opaque 0 offset: keep the 32 V ds_reads inside this iteration
        int vo = 0;
        asm volatile("" : "+v"(vo));

        // O^T = V_pi @ P^T : 4 hd-tiles, k = 256 in 8 chunks of 32
        f32x4 o[4];
#pragma unroll
        for (int nt = 0; nt < 4; ++nt)
#pragma unroll
            for (int rr = 0; rr < 4; ++rr) o[nt][rr] = 0.f;

#pragma unroll
        for (int c = 0; c < 8; ++c) {
            // P^T B-frag: slot (quad, j) <-> kv = 32c + 16*(j>>2) + 4*quad + (j&3)
            f16x8 pb;
#pragma unroll
            for (int j = 0; j < 8; ++j)
                pb[j] = (_Float16)st[2 * c + (j >> 2)][j & 3];
#pragma unroll
            for (int nt = 0; nt < 4; ++nt) {
                const f16x8 va = *(const f16x8*)&Vs[(nt * 16 + l15) * 256 +
                                                   (((c * 4 + quad) ^ vsw) * 8) + vo];
                o[nt] = MFMA16(va, pb, o[nt]);
            }
        }

        // store: O^T C-frag: q = l15, hd = nt*16 + quad*4 + rr -> f16x4 packs
        const size_t rowbase = ((size_t)b * 4096 + q0 + qrow + l15) * 1024 + h * 64;
#pragma unroll
        for (int nt = 0; nt < 4; ++nt) {
            f16x4 ov;
#pragma unroll
            for (int rr = 0; rr < 4; ++rr) ov[rr] = (_Float16)(o[nt][rr] * ir);
            *(f16x4*)&attn[rowbase + nt * 16 + quad * 4] = ov;
        }

        bq0 = nq0; bq1 = nq1;
    }
}

// ---------------------------------------------------------------------------
extern "C" void kernel_launch(void* const* d_in, const int* in_sizes, int n_in,
                              void* d_out, int out_size, void* d_ws, size_t ws_size,
                              hipStream_t stream) {
    const float* patches = (const float*)d_in[0];
    const float* latents = (const float*)d_in[1];
    const float* Wq = (const float*)d_in[2];
    const float* bq = (const float*)d_in[3];
    const float* Wk = (const float*)d_in[4];
    const float* bk = (const float*)d_in[5];
    const float* Wv = (const float*)d_in[6];
    const float* bv = (const float*)d_in[7];
    const float* Wo = (const float*)d_in[8];
    const float* bo = (const float*)d_in[9];
    const int*   nf = (const int*)d_in[10];
    float* out = (float*)d_out;
    (void)in_sizes; (void)n_in; (void)out_size; (void)ws_size;

    char* p = (char*)d_ws;
    _Float16* WqT  = (_Float16*)p; p += (size_t)1024 * 1024 * 2;
    _Float16* WkvT = (_Float16*)p; p += (size_t)512 * 1024 * 2;
    _Float16* WoT  = (_Float16*)p; p += (size_t)1024 * 1024 * 2;
    float*    bkv  = (float*)p;    p += 4096;
    _Float16* p16  = (_Float16*)p; p += (size_t)4 * 4096 * 1024 * 2;
    _Float16* l16  = (_Float16*)p; p += (size_t)4 * 256 * 1024 * 2;
    _Float16* q_h  = (_Float16*)p; p += (size_t)4 * 16 * 4096 * 64 * 2;
    _Float16* k_h  = (_Float16*)p; p += (size_t)4 * 4 * 256 * 64 * 2;
    _Float16* v_pi = (_Float16*)p; p += (size_t)4 * 4 * 256 * 64 * 2;  // after k_h
    _Float16* attn_h = (_Float16*)p; p += (size_t)16384 * 1024 * 2;

    cvt_all<<<17408, 256, 0, stream>>>((const float4*)patches, (const float4*)latents,
                                       (f16x4*)p16, (f16x4*)l16);
    transpose_all<<<dim3(16, 16, 4), 256, 0, stream>>>(Wq, Wk, Wv, Wo, WqT, WkvT, WoT);
    catbias<<<1, 512, 0, stream>>>(bk, bv, bkv);

    gemm32<1><<<dim3(4, 4), 256, 0, stream>>>(l16, WkvT, bkv, k_h, nf);
    gemm8p<0><<<256, 512, 0, stream>>>(p16, WqT, bq, q_h, nf);

    attn5<<<dim3(64, 8), 512, 0, stream>>>(q_h, k_h, v_pi, attn_h);

    gemm8p<2><<<256, 512, 0, stream>>>(attn_h, WoT, bo, out, nf);
}